// Round 17
// baseline (993.519 us; speedup 1.0000x reference)
//
#include <hip/hip_runtime.h>
#include <hip/hip_bf16.h>
#include <hip/hip_cooperative_groups.h>

namespace cg = cooperative_groups;

#define BB 8
#define NN 1024
#define HH 512
#define NHEADS 8
#define UU 64

typedef __attribute__((ext_vector_type(8))) short short8;
typedef __attribute__((ext_vector_type(4))) float f32x4;
typedef __attribute__((ext_vector_type(16))) float f32x16;
typedef unsigned short u16;
typedef unsigned char u8;

__device__ inline float b2f(unsigned short u) {
    union { float f; unsigned int i; } c; c.i = ((unsigned int)u) << 16; return c.f;
}
__device__ inline unsigned short f2b(float f) {
    __hip_bfloat16 h = __float2bfloat16(f);
    return *reinterpret_cast<unsigned short*>(&h);
}
// pack two f32 -> two bf16 (RNE) in one dword via HW cvt: lo16 = a, hi16 = b
__device__ inline unsigned int pkbf(float a, float b) {
    unsigned int r;
    asm("v_cvt_pk_bf16_f32 %0, %1, %2" : "=v"(r) : "v"(a), "v"(b));
    return r;
}
__device__ inline float upk_lo(unsigned int u) {
    union { float f; unsigned int i; } c; c.i = u << 16; return c.f;
}
__device__ inline float upk_hi(unsigned int u) {
    union { float f; unsigned int i; } c; c.i = u & 0xffff0000u; return c.f;
}
// async global->LDS, 16B per lane. lds base wave-uniform; data lands at base + lane*16.
__device__ inline void gl_lds16(const void* g, void* l) {
    __builtin_amdgcn_global_load_lds(
        (const __attribute__((address_space(1))) unsigned int*)g,
        (__attribute__((address_space(3))) unsigned int*)l, 16, 0, 0);
}

// ---------------------------------------------------------------------------
// K0: fused preprocessing. gid<2048: x fp32->bf16; gid<2432: W fp32->bf16;
// gid>=2432: adj -> transposed bitmask adjpT[b][kdword(32)][row(1024)].
// ---------------------------------------------------------------------------
__global__ __launch_bounds__(256) void prep(
    const float* __restrict__ x, const float* __restrict__ Wq,
    const float* __restrict__ Wk, const float* __restrict__ Wv,
    const int* __restrict__ adj,
    u16* __restrict__ xb, u16* __restrict__ Wb,
    unsigned int* __restrict__ adjpT)
{
    const int gid = blockIdx.x;
    if (gid < 2432) {
        const float* src;
        u16* dst;
        int base;
        if (gid < 2048) {
            src = x; dst = xb;
            base = (gid * 256 + threadIdx.x) * 8;
        } else {
            const int g = gid - 2048;          // 0..383
            const int which = g >> 7;          // /128
            const int slice = g & 127;
            src = which == 0 ? Wq : (which == 1 ? Wk : Wv);
            dst = Wb + (size_t)which * HH * HH;
            base = (slice * 256 + threadIdx.x) * 8;
        }
        const float4* sp = (const float4*)&src[base];
        float4 a = sp[0], b = sp[1];
        short8 o;
        o[0] = (short)f2b(a.x); o[1] = (short)f2b(a.y);
        o[2] = (short)f2b(a.z); o[3] = (short)f2b(a.w);
        o[4] = (short)f2b(b.x); o[5] = (short)f2b(b.y);
        o[6] = (short)f2b(b.z); o[7] = (short)f2b(b.w);
        *(short8*)&dst[base] = o;
    } else {
        const int wave = threadIdx.x >> 6, lane = threadIdx.x & 63;
        const int row = (gid - 2432) * 4 + wave;        // 0..8191
        const int b = row >> 10, r = row & 1023;
        const int* ar = adj + (size_t)row * NN;
        unsigned int* ob = adjpT + (((size_t)b) << 15) + r;   // b*32*1024 + r
        #pragma unroll
        for (int it = 0; it < 16; ++it) {
            int a = ar[it * 64 + lane];
            unsigned long long m = __ballot(a != 0);
            if (lane == 0) {
                ob[(size_t)(2 * it)     << 10] = (unsigned int)m;
                ob[(size_t)(2 * it + 1) << 10] = (unsigned int)(m >> 32);
            }
        }
    }
}

// ---------------------------------------------------------------------------
// K1: y = x @ W^T + b (q,k,v via blockIdx.z). 128x128 tile, BK=32.
// Double-buffered staging, one barrier per K-step; Cs unioned onto staging
// buffers (34.8KB LDS, 4 blocks/CU). which==2 also emits v^T fp8 from Cs.
// ---------------------------------------------------------------------------
__global__ __launch_bounds__(256, 4) void qkv_gemm(
    const u16* __restrict__ xb, const u16* __restrict__ Wb,
    const float* __restrict__ bq, const float* __restrict__ bk,
    const float* __restrict__ bv,
    u16* __restrict__ q, u16* __restrict__ k, u16* __restrict__ v,
    u8* __restrict__ v8t)
{
    const int which = blockIdx.z;
    const u16* W      = Wb + (size_t)which * HH * HH;
    const float* bias = which == 0 ? bq : (which == 1 ? bk : bv);
    u16* out          = which == 0 ? q  : (which == 1 ? k  : v);

    const int tid = threadIdx.x;
    const int wave = tid >> 6, lane = tid & 63;
    const int ln = lane & 15, quad = lane >> 4;
    const int wr = (wave >> 1) * 64, wc = (wave & 1) * 64;
    const int rowbase = blockIdx.x * 128, colbase = blockIdx.y * 128;

    __shared__ __align__(16) char smem[128 * 136 * 2];
    u16* Cs = (u16*)smem;

    f32x4 acc[4][4];
    #pragma unroll
    for (int ri = 0; ri < 4; ++ri)
        #pragma unroll
        for (int ci = 0; ci < 4; ++ci) acc[ri][ci] = (f32x4){0.f, 0.f, 0.f, 0.f};

    const int lr = lane >> 2;          // row-in-16
    const int sg = lane & 3;           // 8-elem k-segment

    auto STAGE = [&](int buf, int kk) {
        char* Ab = smem + buf * 16384;
        char* Bb = smem + 8192 + buf * 16384;
        #pragma unroll
        for (int i = 0; i < 2; ++i) {
            int r = wave * 32 + i * 16 + lr;
            gl_lds16(&xb[(size_t)(rowbase + r) * HH + kk + sg * 8],
                     Ab + (wave * 32 + i * 16) * 64);
            gl_lds16(&W[(size_t)(colbase + r) * HH + kk + sg * 8],
                     Bb + (wave * 32 + i * 16) * 64);
        }
    };

    STAGE(0, 0);
    for (int s = 0; s < 16; ++s) {
        __syncthreads();               // buf (s&1) staged; prev reads done
        if (s < 15) STAGE((s + 1) & 1, (s + 1) * 32);
        const u16* As = (const u16*)(smem + (s & 1) * 16384);
        const u16* Bs = (const u16*)(smem + 8192 + (s & 1) * 16384);

        short8 bfr[4];
        #pragma unroll
        for (int ci = 0; ci < 4; ++ci)
            bfr[ci] = *(const short8*)&Bs[(wc + ci * 16 + ln) * 32 + quad * 8];
        #pragma unroll
        for (int ri = 0; ri < 4; ++ri) {
            short8 af = *(const short8*)&As[(wr + ri * 16 + ln) * 32 + quad * 8];
            #pragma unroll
            for (int ci = 0; ci < 4; ++ci)
                acc[ri][ci] = __builtin_amdgcn_mfma_f32_16x16x32_bf16(af, bfr[ci], acc[ri][ci], 0, 0, 0);
        }
    }

    __syncthreads();   // all As/Bs reads done before Cs overwrites the union
    #pragma unroll
    for (int ci = 0; ci < 4; ++ci) {
        int col = wc + ci * 16 + ln;
        float bb = bias[colbase + col];
        #pragma unroll
        for (int ri = 0; ri < 4; ++ri) {
            #pragma unroll
            for (int r = 0; r < 4; ++r) {
                int row = wr + ri * 16 + quad * 4 + r;
                Cs[row * 136 + col] = f2b(acc[ri][ci][r] + bb);
            }
        }
    }
    __syncthreads();
    {
        int row = tid >> 1, half = tid & 1;
        int gcol0 = colbase + half * 64;
        int hh = gcol0 >> 6;
        int grow = rowbase + row;
        int bidx = grow >> 10, n = grow & 1023;
        u16* op = &out[(((size_t)(bidx * NHEADS + hh)) * NN + n) * UU];
        const u16* cp = &Cs[row * 136 + half * 64];
        #pragma unroll
        for (int j = 0; j < 8; ++j)
            *(short8*)(op + j * 8) = *(const short8*)(cp + j * 8);
    }
    if (which == 2) {
        const int d_local = tid >> 1, nh = tid & 1;
        const int hloc = d_local >> 6, d = d_local & 63;
        const int bidx = rowbase >> 10, n0 = (rowbase & 1023) + nh * 64;
        const int bh = bidx * NHEADS + (colbase >> 6) + hloc;
        u8* vp = v8t + ((size_t)bh << 16) + (size_t)d * 1024 + n0;
        #pragma unroll
        for (int j = 0; j < 16; ++j) {
            const u16* cp = &Cs[(nh * 64 + j * 4) * 136 + d_local];
            float f0 = b2f(cp[0]);
            float f1 = b2f(cp[136]);
            float f2 = b2f(cp[272]);
            float f3 = b2f(cp[408]);
            int lo = __builtin_amdgcn_cvt_pk_fp8_f32(f0, f1, 0, false);
            unsigned int dw = (unsigned int)__builtin_amdgcn_cvt_pk_fp8_f32(f2, f3, lo, true);
            *(unsigned int*)(vp + j * 4) = dw;
        }
    }
}

// ---------------------------------------------------------------------------
// K2: scores+softmax, swapped-operand 32x32 S^T formulation (verified):
// single K pass, eb 32-VGPR cache, coalesced 16B stores via shfl_xor(32)
// pair-exchange, XCD-colocating decode.
// ---------------------------------------------------------------------------
__global__ __launch_bounds__(512, 4) void scores_softmax(
    const u16* __restrict__ q, const u16* __restrict__ kmat,
    const unsigned int* __restrict__ adjpT, u8* __restrict__ P8)
{
    const int gid = blockIdx.x;
    const int j = gid >> 3;
    const int h = gid & 7;
    const int b = j >> 5;
    const int bx = j & 31;
    const int bh = b * NHEADS + h;

    const int tid = threadIdx.x;
    const int kq = tid >> 6, lane = tid & 63;     // kq 0..7
    const int l31 = lane & 31, hi = lane >> 5;
    const int n = bx * 32 + l31;                  // q-row within bh
    const int kt0 = kq * 4;                       // this wave's first 32-k tile

    __shared__ float rs[8][32];

    short8 qf[4];
    const u16* qp = &q[((size_t)bh * NN + n) * UU + hi * 8];
    #pragma unroll
    for (int f = 0; f < 4; ++f) qf[f] = *(const short8*)(qp + f * 16);

    const u16* kbase = kmat + (size_t)bh * NN * UU + (size_t)(kt0 * 32 + l31) * UU + hi * 8;
    const unsigned int* mbase = adjpT + (((size_t)b) << 15) + n;

    unsigned int mv[4];
    #pragma unroll
    for (int i = 0; i < 4; ++i)
        mv[i] = mbase[(size_t)(kt0 + i) << 10] >> (4 * hi);

    const float L2E = 1.442695041f;
    const float C0 = -46.16624f;      // 1.4427 * (-32)
    const float CM = -100000.0f;      // masked-off -> exp2 == 0

    unsigned int eb[4][4][2];         // 32 VGPRs, fully statically indexed
    float rs0 = 0.f, rs1 = 0.f, rs2 = 0.f, rs3 = 0.f;

    short8 kf[4];
    #pragma unroll
    for (int f = 0; f < 4; ++f) kf[f] = *(const short8*)(kbase + f * 16);

    #pragma unroll
    for (int i = 0; i < 4; ++i) {
        f32x16 acc;
        #pragma unroll
        for (int jj = 0; jj < 16; ++jj) acc[jj] = 0.f;
        #pragma unroll
        for (int f = 0; f < 4; ++f)
            acc = __builtin_amdgcn_mfma_f32_32x32x16_bf16(kf[f], qf[f], acc, 0, 0, 0);
        if (i < 3) {
            const u16* kn = kbase + (size_t)(i + 1) * (32 * UU);
            #pragma unroll
            for (int f = 0; f < 4; ++f) kf[f] = *(const short8*)(kn + f * 16);
        }
        const unsigned int m2 = mv[i];
        #pragma unroll
        for (int g = 0; g < 4; ++g) {
            float e[4];
            #pragma unroll
            for (int r = 0; r < 4; ++r) {
                const int koff = r + 8 * g;
                float addv = ((m2 >> koff) & 1u) ? C0 : CM;
                e[r] = __builtin_amdgcn_exp2f(fmaf(L2E, acc[g * 4 + r], addv));
            }
            if (g == 0) rs0 += (e[0] + e[1]) + (e[2] + e[3]);
            else if (g == 1) rs1 += (e[0] + e[1]) + (e[2] + e[3]);
            else if (g == 2) rs2 += (e[0] + e[1]) + (e[2] + e[3]);
            else rs3 += (e[0] + e[1]) + (e[2] + e[3]);
            eb[i][g][0] = pkbf(e[0], e[1]);
            eb[i][g][1] = pkbf(e[2], e[3]);
        }
    }
    float rsum = (rs0 + rs1) + (rs2 + rs3);
    rsum += __shfl_xor(rsum, 32);          // lanes l / l+32 cover complementary k
    if (lane < 32) rs[kq][lane] = rsum;
    __syncthreads();
    const float total = ((rs[0][l31] + rs[1][l31]) + (rs[2][l31] + rs[3][l31]))
                      + ((rs[4][l31] + rs[5][l31]) + (rs[6][l31] + rs[7][l31]));
    const float scl = 16.0f / total;       // x16 folded; undone by 0.9/16 in hop

    u8* pb = P8 + (((size_t)bh) << 20) + (size_t)(n >> 4) * 16384
           + (n & 15) * 32 + hi * 16;
    #pragma unroll
    for (int i = 0; i < 4; ++i) {
        unsigned int dw[4];
        #pragma unroll
        for (int g = 0; g < 4; ++g) {      // reg quad g -> k bytes 8g+4hi .. +4
            float e0 = upk_lo(eb[i][g][0]) * scl;
            float e1 = upk_hi(eb[i][g][0]) * scl;
            float e2 = upk_lo(eb[i][g][1]) * scl;
            float e3 = upk_hi(eb[i][g][1]) * scl;
            int lo = __builtin_amdgcn_cvt_pk_fp8_f32(e0, e1, 0, false);
            dw[g] = (unsigned int)__builtin_amdgcn_cvt_pk_fp8_f32(e2, e3, lo, true);
        }
        unsigned int sendA = hi ? dw[0] : dw[2];
        unsigned int sendB = hi ? dw[1] : dw[3];
        unsigned int recvA = (unsigned int)__shfl_xor((int)sendA, 32);
        unsigned int recvB = (unsigned int)__shfl_xor((int)sendB, 32);
        uint4 o;
        o.x = hi ? recvA : dw[0];
        o.y = hi ? dw[2] : recvA;
        o.z = hi ? recvB : dw[1];
        o.w = hi ? dw[3] : recvB;
        *(uint4*)(pb + (size_t)(kt0 + i) * 512) = o;
    }
}

// ---------------------------------------------------------------------------
// K3a: hop4 — all four hops in one cooperative kernel. Block loads its 16KB
// P-tile into registers ONCE (32 static longs); per iter: {MFMAs from reg-P
// vs LDS-staged z -> write z' -> fence+grid.sync+fence -> stage next z}.
// iter0: v8t->z8a; iter1: z8a->z8b; iter2: z8b->z8a; iter3: -> za bf16.
// Host falls back to the 4-launch classic hop if cooperative launch errors.
// ---------------------------------------------------------------------------
__global__ __launch_bounds__(512, 4) void hop4(
    const u8* __restrict__ P8, const u8* __restrict__ v8t,
    const u16* __restrict__ v, u8* __restrict__ z8a, u8* __restrict__ z8b,
    u16* __restrict__ zbf_out)
{
    const int b = blockIdx.z, h = blockIdx.y, rt = blockIdx.x;
    const int bh = b * NHEADS + h;
    const int tid = threadIdx.x;
    const int wave = tid >> 6, lane = tid & 63;
    const int ln = lane & 15, quad = lane >> 4;
    const int wrow = rt * 128 + wave * 16;

    __shared__ __align__(16) u8 zt[64 * 1040];

    // stage iter0's z (= v8t) first so the P loads overlap it
    const u8* zg0 = v8t + ((size_t)bh << 16);
    #pragma unroll
    for (int i = 0; i < 8; ++i) {
        int c = wave * 8 + i;
        gl_lds16(zg0 + (size_t)c * 1024 + lane * 16, (char*)zt + c * 1040);
    }

    // P-tile -> registers, once (32 longs, statically indexed)
    const u8* pt = P8 + ((size_t)bh << 20) + (size_t)(rt * 8 + wave) * 16384
                 + ln * 32 + quad * 8;
    long P[32];
    #pragma unroll
    for (int kc = 0; kc < 32; ++kc) P[kc] = *(const long*)(pt + kc * 512);

    cg::grid_group grid = cg::this_grid();

    __syncthreads();    // zt ready (barrier drains the gl_lds16 queue)

    const u8* srcs1to3[3] = { z8a, z8b, z8a };  // z source for iters 1,2,3
    u8* dsts[3] = { z8a, z8b, z8a };            // z dest for iters 0,1,2

    #pragma unroll 1
    for (int iter = 0; iter < 4; ++iter) {
        f32x4 acc[4];
        #pragma unroll
        for (int ci = 0; ci < 4; ++ci) acc[ci] = (f32x4){0.f, 0.f, 0.f, 0.f};

        #pragma unroll
        for (int kc = 0; kc < 32; ++kc) {
            int kk = kc * 32;
            #pragma unroll
            for (int ci = 0; ci < 4; ++ci) {
                long bz = *(const long*)&zt[(ci * 16 + ln) * 1040 + kk + quad * 8];
                acc[ci] = __builtin_amdgcn_mfma_f32_16x16x32_fp8_fp8(P[kc], bz, acc[ci], 0, 0, 0);
            }
        }

        if (iter == 3) {
            #pragma unroll
            for (int ci = 0; ci < 4; ++ci) {
                int col = ci * 16 + ln;
                #pragma unroll
                for (int r = 0; r < 4; ++r) {
                    int row = wrow + quad * 4 + r;
                    float vv = b2f(v[((size_t)bh * NN + row) * UU + col]);
                    zbf_out[((size_t)(b * NN + row)) * HH + h * UU + col]
                        = f2b(0.05625f * acc[ci][r] + 0.1f * vv);
                }
            }
        } else {
            u8* zo = dsts[iter] + ((size_t)bh << 16);
            #pragma unroll
            for (int ci = 0; ci < 4; ++ci) {
                int col = ci * 16 + ln;
                float zv[4];
                #pragma unroll
                for (int r = 0; r < 4; ++r) {
                    int row = wrow + quad * 4 + r;
                    float vv = b2f(v[((size_t)bh * NN + row) * UU + col]);
                    zv[r] = 0.05625f * acc[ci][r] + 0.1f * vv;
                }
                int lo = __builtin_amdgcn_cvt_pk_fp8_f32(zv[0], zv[1], 0, false);
                unsigned int dw = (unsigned int)__builtin_amdgcn_cvt_pk_fp8_f32(zv[2], zv[3], lo, true);
                *(unsigned int*)&zo[(size_t)col * 1024 + wrow + quad * 4] = dw;
            }
            __threadfence();   // release all z' writes to device scope
            grid.sync();
            __threadfence();   // acquire: invalidate stale cached z
            // stage next iteration's z
            const u8* zsrc = srcs1to3[iter] + ((size_t)bh << 16);
            #pragma unroll
            for (int i = 0; i < 8; ++i) {
                int c = wave * 8 + i;
                gl_lds16(zsrc + (size_t)c * 1024 + lane * 16, (char*)zt + c * 1040);
            }
            __syncthreads();   // zt ready for next iter
        }
    }
}

// ---------------------------------------------------------------------------
// K3b: classic hop (verified R8/R15) — fallback if cooperative launch fails.
// ---------------------------------------------------------------------------
__global__ __launch_bounds__(512) void hop(
    const u8* __restrict__ P8, const u8* __restrict__ z8in,
    const u16* __restrict__ v, u8* __restrict__ z8out,
    u16* __restrict__ zbf_out, int last)
{
    const int b = blockIdx.z, h = blockIdx.y, rt = blockIdx.x;
    const int bh = b * NHEADS + h;
    const int tid = threadIdx.x;
    const int wave = tid >> 6, lane = tid & 63;
    const int ln = lane & 15, quad = lane >> 4;
    const int wrow = rt * 128 + wave * 16;

    __shared__ __align__(16) u8 zt[64 * 1040];

    const u8* zg = z8in + ((size_t)bh << 16);
    #pragma unroll
    for (int i = 0; i < 8; ++i) {
        int c = wave * 8 + i;
        gl_lds16(zg + (size_t)c * 1024 + lane * 16, (char*)zt + c * 1040);
    }

    const u8* pt = P8 + ((size_t)bh << 20) + (size_t)(rt * 8 + wave) * 16384
                 + ln * 32 + quad * 8;
    long pa[4];
    #pragma unroll
    for (int i = 0; i < 4; ++i) pa[i] = *(const long*)(pt + i * 512);

    __syncthreads();

    f32x4 acc[4];
    #pragma unroll
    for (int ci = 0; ci < 4; ++ci) acc[ci] = (f32x4){0.f, 0.f, 0.f, 0.f};

    #pragma unroll
    for (int kc = 0; kc < 32; ++kc) {
        long a = pa[kc & 3];
        if (kc + 4 < 32) pa[kc & 3] = *(const long*)(pt + (kc + 4) * 512);
        int kk = kc * 32;
        #pragma unroll
        for (int ci = 0; ci < 4; ++ci) {
            long bz = *(const long*)&zt[(ci * 16 + ln) * 1040 + kk + quad * 8];
            acc[ci] = __builtin_amdgcn_mfma_f32_16x16x32_fp8_fp8(a, bz, acc[ci], 0, 0, 0);
        }
    }

    if (last) {
        #pragma unroll
        for (int ci = 0; ci < 4; ++ci) {
            int col = ci * 16 + ln;
            #pragma unroll
            for (int r = 0; r < 4; ++r) {
                int row = wrow + quad * 4 + r;
                float vv = b2f(v[((size_t)bh * NN + row) * UU + col]);
                zbf_out[((size_t)(b * NN + row)) * HH + h * UU + col]
                    = f2b(0.05625f * acc[ci][r] + 0.1f * vv);
            }
        }
    } else {
        u8* zo = z8out + ((size_t)bh << 16);
        #pragma unroll
        for (int ci = 0; ci < 4; ++ci) {
            int col = ci * 16 + ln;
            float zv[4];
            #pragma unroll
            for (int r = 0; r < 4; ++r) {
                int row = wrow + quad * 4 + r;
                float vv = b2f(v[((size_t)bh * NN + row) * UU + col]);
                zv[r] = 0.05625f * acc[ci][r] + 0.1f * vv;
            }
            int lo = __builtin_amdgcn_cvt_pk_fp8_f32(zv[0], zv[1], 0, false);
            unsigned int dw = (unsigned int)__builtin_amdgcn_cvt_pk_fp8_f32(zv[2], zv[3], lo, true);
            *(unsigned int*)&zo[(size_t)col * 1024 + wrow + quad * 4] = dw;
        }
    }
}

// ---------------------------------------------------------------------------
// K4: y = x + z ; LayerNorm(y)*gamma + beta. x fp32, z bf16 [b,n,512], out fp32.
// ---------------------------------------------------------------------------
__global__ __launch_bounds__(256) void resid_ln(
    const float* __restrict__ x, const u16* __restrict__ z,
    const float* __restrict__ gamma, const float* __restrict__ beta,
    float* __restrict__ out)
{
    const int r = blockIdx.x * 4 + (threadIdx.x >> 6);
    const int lane = threadIdx.x & 63;
    const size_t base = (size_t)r * HH + lane * 8;

    const float4* xp = (const float4*)&x[base];
    float4 x0 = xp[0], x1 = xp[1];
    short8 zv = *(const short8*)&z[base];
    float y[8];
    y[0] = x0.x + b2f((u16)zv[0]); y[1] = x0.y + b2f((u16)zv[1]);
    y[2] = x0.z + b2f((u16)zv[2]); y[3] = x0.w + b2f((u16)zv[3]);
    y[4] = x1.x + b2f((u16)zv[4]); y[5] = x1.y + b2f((u16)zv[5]);
    y[6] = x1.z + b2f((u16)zv[6]); y[7] = x1.w + b2f((u16)zv[7]);

    float s = 0.f, sq = 0.f;
    #pragma unroll
    for (int j = 0; j < 8; ++j) { s += y[j]; sq += y[j] * y[j]; }
    #pragma unroll
    for (int off = 32; off >= 1; off >>= 1) {
        s  += __shfl_xor(s, off);
        sq += __shfl_xor(sq, off);
    }
    const float mu = s * (1.0f / HH);
    const float var = sq * (1.0f / HH) - mu * mu;
    const float rstd = rsqrtf(var + 1e-5f);

    const float4* gp = (const float4*)&gamma[lane * 8];
    const float4* bp = (const float4*)&beta[lane * 8];
    float4 g0 = gp[0], g1 = gp[1], b0 = bp[0], b1 = bp[1];

    float4 o0, o1;
    o0.x = (y[0] - mu) * rstd * g0.x + b0.x;
    o0.y = (y[1] - mu) * rstd * g0.y + b0.y;
    o0.z = (y[2] - mu) * rstd * g0.z + b0.z;
    o0.w = (y[3] - mu) * rstd * g0.w + b0.w;
    o1.x = (y[4] - mu) * rstd * g1.x + b1.x;
    o1.y = (y[5] - mu) * rstd * g1.y + b1.y;
    o1.z = (y[6] - mu) * rstd * g1.z + b1.z;
    o1.w = (y[7] - mu) * rstd * g1.w + b1.w;
    float4* op = (float4*)&out[base];
    op[0] = o0; op[1] = o1;
}

// ---------------------------------------------------------------------------
extern "C" void kernel_launch(void* const* d_in, const int* in_sizes, int n_in,
                              void* d_out, int out_size, void* d_ws, size_t ws_size,
                              hipStream_t stream)
{
    const float* x   = (const float*)d_in[0];
    const int* adj   = (const int*)d_in[1];
    const float* Wq  = (const float*)d_in[2];
    const float* bq  = (const float*)d_in[3];
    const float* Wk  = (const float*)d_in[4];
    const float* bk  = (const float*)d_in[5];
    const float* Wv  = (const float*)d_in[6];
    const float* bv  = (const float*)d_in[7];
    const float* gamma = (const float*)d_in[8];
    const float* beta  = (const float*)d_in[9];
    float* out = (float*)d_out;

    const size_t E = (size_t)BB * NN * HH;   // 4,194,304
    u16* ws16 = (u16*)d_ws;
    u16* xb = ws16;          // x as bf16, [b,n,512]
    u16* q  = ws16 + E;      // per-head layout [bh][n][64]
    u16* k  = ws16 + 2 * E;  // per-head layout
    u16* v  = ws16 + 3 * E;  // per-head layout
    u16* za = ws16 + 4 * E;  // final z, bf16, [b,n,512]
    u16* Wb = ws16 + 5 * E;  // 786,432 elems
    u8* base8 = (u8*)(ws16 + 5 * E + 786432);
    u8* P8  = base8;                          // 64 MB, tiled layout
    u8* z8a = base8 + ((size_t)64 << 20);     // 4 MB
    u8* z8b = z8a + ((size_t)4 << 20);        // 4 MB
    u8* v8t = z8b + ((size_t)4 << 20);        // 4 MB
    unsigned int* adjpT = (unsigned int*)(v8t + ((size_t)4 << 20));  // 1 MB

    prep<<<dim3(4480), 256, 0, stream>>>(x, Wq, Wk, Wv, adj, xb, Wb, adjpT);
    qkv_gemm<<<dim3(64, 4, 3), 256, 0, stream>>>(xb, Wb, bq, bk, bv, q, k, v, v8t);
    scores_softmax<<<dim3(2048), 512, 0, stream>>>(q, k, adjpT, P8);

    {
        void* args[] = { (void*)&P8, (void*)&v8t, (void*)&v,
                         (void*)&z8a, (void*)&z8b, (void*)&za };
        hipError_t ce = hipLaunchCooperativeKernel(
            (const void*)hop4, dim3(8, NHEADS, BB), dim3(512), args, 0, stream);
        if (ce != hipSuccess) {
            // cooperative launch unsupported (e.g. under graph capture):
            // fall back to the verified 4-launch pipeline.
            hop<<<dim3(8, NHEADS, BB), 512, 0, stream>>>(P8, v8t, v, z8a, za, 0);
            hop<<<dim3(8, NHEADS, BB), 512, 0, stream>>>(P8, z8a, v, z8b, za, 0);
            hop<<<dim3(8, NHEADS, BB), 512, 0, stream>>>(P8, z8b, v, z8a, za, 0);
            hop<<<dim3(8, NHEADS, BB), 512, 0, stream>>>(P8, z8a, v, z8b, za, 1);
        }
    }

    resid_ln<<<dim3(2048), 256, 0, stream>>>(x, za, gamma, beta, out);
}

// Round 18
// 261.480 us; speedup vs baseline: 3.7996x; 3.7996x over previous
//
#include <hip/hip_runtime.h>
#include <hip/hip_bf16.h>

#define BB 8
#define NN 1024
#define HH 512
#define NHEADS 8
#define UU 64

typedef __attribute__((ext_vector_type(8))) short short8;
typedef __attribute__((ext_vector_type(4))) float f32x4;
typedef __attribute__((ext_vector_type(16))) float f32x16;
typedef unsigned short u16;
typedef unsigned char u8;

__device__ inline float b2f(unsigned short u) {
    union { float f; unsigned int i; } c; c.i = ((unsigned int)u) << 16; return c.f;
}
__device__ inline unsigned short f2b(float f) {
    __hip_bfloat16 h = __float2bfloat16(f);
    return *reinterpret_cast<unsigned short*>(&h);
}
// pack two f32 -> two bf16 (RNE) in one dword via HW cvt: lo16 = a, hi16 = b
__device__ inline unsigned int pkbf(float a, float b) {
    unsigned int r;
    asm("v_cvt_pk_bf16_f32 %0, %1, %2" : "=v"(r) : "v"(a), "v"(b));
    return r;
}
__device__ inline float upk_lo(unsigned int u) {
    union { float f; unsigned int i; } c; c.i = u << 16; return c.f;
}
__device__ inline float upk_hi(unsigned int u) {
    union { float f; unsigned int i; } c; c.i = u & 0xffff0000u; return c.f;
}
// async global->LDS, 16B per lane. lds base wave-uniform; data lands at base + lane*16.
__device__ inline void gl_lds16(const void* g, void* l) {
    __builtin_amdgcn_global_load_lds(
        (const __attribute__((address_space(1))) unsigned int*)g,
        (__attribute__((address_space(3))) unsigned int*)l, 16, 0, 0);
}

// ---------------------------------------------------------------------------
// K0: fused preprocessing. gid<2048: x fp32->bf16; gid<2432: W fp32->bf16;
// gid>=2432: adj -> transposed bitmask adjpT[b][kdword(32)][row(1024)].
// ---------------------------------------------------------------------------
__global__ __launch_bounds__(256) void prep(
    const float* __restrict__ x, const float* __restrict__ Wq,
    const float* __restrict__ Wk, const float* __restrict__ Wv,
    const int* __restrict__ adj,
    u16* __restrict__ xb, u16* __restrict__ Wb,
    unsigned int* __restrict__ adjpT)
{
    const int gid = blockIdx.x;
    if (gid < 2432) {
        const float* src;
        u16* dst;
        int base;
        if (gid < 2048) {
            src = x; dst = xb;
            base = (gid * 256 + threadIdx.x) * 8;
        } else {
            const int g = gid - 2048;          // 0..383
            const int which = g >> 7;          // /128
            const int slice = g & 127;
            src = which == 0 ? Wq : (which == 1 ? Wk : Wv);
            dst = Wb + (size_t)which * HH * HH;
            base = (slice * 256 + threadIdx.x) * 8;
        }
        const float4* sp = (const float4*)&src[base];
        float4 a = sp[0], b = sp[1];
        short8 o;
        o[0] = (short)f2b(a.x); o[1] = (short)f2b(a.y);
        o[2] = (short)f2b(a.z); o[3] = (short)f2b(a.w);
        o[4] = (short)f2b(b.x); o[5] = (short)f2b(b.y);
        o[6] = (short)f2b(b.z); o[7] = (short)f2b(b.w);
        *(short8*)&dst[base] = o;
    } else {
        const int wave = threadIdx.x >> 6, lane = threadIdx.x & 63;
        const int row = (gid - 2432) * 4 + wave;        // 0..8191
        const int b = row >> 10, r = row & 1023;
        const int* ar = adj + (size_t)row * NN;
        unsigned int* ob = adjpT + (((size_t)b) << 15) + r;   // b*32*1024 + r
        #pragma unroll
        for (int it = 0; it < 16; ++it) {
            int a = ar[it * 64 + lane];
            unsigned long long m = __ballot(a != 0);
            if (lane == 0) {
                ob[(size_t)(2 * it)     << 10] = (unsigned int)m;
                ob[(size_t)(2 * it + 1) << 10] = (unsigned int)(m >> 32);
            }
        }
    }
}

// ---------------------------------------------------------------------------
// K1: y = x @ W^T + b (q,k,v via blockIdx.z). 128x128 tile, BK=32.
// Double-buffered staging, one barrier per K-step; Cs unioned onto staging
// buffers (34.8KB LDS, 4 blocks/CU).
// For which==2 the epilogue ALSO emits v^T fp8 (v8t[bh][d][n]) straight
// from Cs — vt8 kernel deleted (saves its HBM round-trip + a launch).
// ---------------------------------------------------------------------------
__global__ __launch_bounds__(256, 4) void qkv_gemm(
    const u16* __restrict__ xb, const u16* __restrict__ Wb,
    const float* __restrict__ bq, const float* __restrict__ bk,
    const float* __restrict__ bv,
    u16* __restrict__ q, u16* __restrict__ k, u16* __restrict__ v,
    u8* __restrict__ v8t)
{
    const int which = blockIdx.z;
    const u16* W      = Wb + (size_t)which * HH * HH;
    const float* bias = which == 0 ? bq : (which == 1 ? bk : bv);
    u16* out          = which == 0 ? q  : (which == 1 ? k  : v);

    const int tid = threadIdx.x;
    const int wave = tid >> 6, lane = tid & 63;
    const int ln = lane & 15, quad = lane >> 4;
    const int wr = (wave >> 1) * 64, wc = (wave & 1) * 64;
    const int rowbase = blockIdx.x * 128, colbase = blockIdx.y * 128;

    __shared__ __align__(16) char smem[128 * 136 * 2];
    u16* Cs = (u16*)smem;

    f32x4 acc[4][4];
    #pragma unroll
    for (int ri = 0; ri < 4; ++ri)
        #pragma unroll
        for (int ci = 0; ci < 4; ++ci) acc[ri][ci] = (f32x4){0.f, 0.f, 0.f, 0.f};

    const int lr = lane >> 2;          // row-in-16
    const int sg = lane & 3;           // 8-elem k-segment

    auto STAGE = [&](int buf, int kk) {
        char* Ab = smem + buf * 16384;
        char* Bb = smem + 8192 + buf * 16384;
        #pragma unroll
        for (int i = 0; i < 2; ++i) {
            int r = wave * 32 + i * 16 + lr;
            gl_lds16(&xb[(size_t)(rowbase + r) * HH + kk + sg * 8],
                     Ab + (wave * 32 + i * 16) * 64);
            gl_lds16(&W[(size_t)(colbase + r) * HH + kk + sg * 8],
                     Bb + (wave * 32 + i * 16) * 64);
        }
    };

    STAGE(0, 0);
    for (int s = 0; s < 16; ++s) {
        __syncthreads();               // buf (s&1) staged; prev reads done
        if (s < 15) STAGE((s + 1) & 1, (s + 1) * 32);
        const u16* As = (const u16*)(smem + (s & 1) * 16384);
        const u16* Bs = (const u16*)(smem + 8192 + (s & 1) * 16384);

        short8 bfr[4];
        #pragma unroll
        for (int ci = 0; ci < 4; ++ci)
            bfr[ci] = *(const short8*)&Bs[(wc + ci * 16 + ln) * 32 + quad * 8];
        #pragma unroll
        for (int ri = 0; ri < 4; ++ri) {
            short8 af = *(const short8*)&As[(wr + ri * 16 + ln) * 32 + quad * 8];
            #pragma unroll
            for (int ci = 0; ci < 4; ++ci)
                acc[ri][ci] = __builtin_amdgcn_mfma_f32_16x16x32_bf16(af, bfr[ci], acc[ri][ci], 0, 0, 0);
        }
    }

    __syncthreads();   // all As/Bs reads done before Cs overwrites the union
    #pragma unroll
    for (int ci = 0; ci < 4; ++ci) {
        int col = wc + ci * 16 + ln;
        float bb = bias[colbase + col];
        #pragma unroll
        for (int ri = 0; ri < 4; ++ri) {
            #pragma unroll
            for (int r = 0; r < 4; ++r) {
                int row = wr + ri * 16 + quad * 4 + r;
                Cs[row * 136 + col] = f2b(acc[ri][ci][r] + bb);
            }
        }
    }
    __syncthreads();
    {
        int row = tid >> 1, half = tid & 1;
        int gcol0 = colbase + half * 64;
        int hh = gcol0 >> 6;
        int grow = rowbase + row;
        int bidx = grow >> 10, n = grow & 1023;
        u16* op = &out[(((size_t)(bidx * NHEADS + hh)) * NN + n) * UU];
        const u16* cp = &Cs[row * 136 + half * 64];
        #pragma unroll
        for (int j = 0; j < 8; ++j)
            *(short8*)(op + j * 8) = *(const short8*)(cp + j * 8);
    }
    if (which == 2) {
        // emit v^T fp8 from Cs: thread t -> d_local = t>>1 (0..127),
        // n-half = t&1 (n0.. or n0+64..); 16 dwords of 4 consecutive n each.
        const int d_local = tid >> 1, nh = tid & 1;
        const int hloc = d_local >> 6, d = d_local & 63;
        const int bidx = rowbase >> 10, n0 = (rowbase & 1023) + nh * 64;
        const int bh = bidx * NHEADS + (colbase >> 6) + hloc;
        u8* vp = v8t + ((size_t)bh << 16) + (size_t)d * 1024 + n0;
        #pragma unroll
        for (int j = 0; j < 16; ++j) {
            const u16* cp = &Cs[(nh * 64 + j * 4) * 136 + d_local];
            float f0 = b2f(cp[0]);
            float f1 = b2f(cp[136]);
            float f2 = b2f(cp[272]);
            float f3 = b2f(cp[408]);
            int lo = __builtin_amdgcn_cvt_pk_fp8_f32(f0, f1, 0, false);
            unsigned int dw = (unsigned int)__builtin_amdgcn_cvt_pk_fp8_f32(f2, f3, lo, true);
            *(unsigned int*)(vp + j * 4) = dw;
        }
    }
}

// ---------------------------------------------------------------------------
// K2: scores+softmax, swapped-operand 32x32 S^T formulation (verified):
// single K pass, eb 32-VGPR cache, coalesced 16B stores via shfl_xor(32)
// pair-exchange, XCD-colocating decode, pipelined K-fragment loads.
// ---------------------------------------------------------------------------
__global__ __launch_bounds__(512, 4) void scores_softmax(
    const u16* __restrict__ q, const u16* __restrict__ kmat,
    const unsigned int* __restrict__ adjpT, u8* __restrict__ P8)
{
    const int gid = blockIdx.x;
    const int j = gid >> 3;
    const int h = gid & 7;
    const int b = j >> 5;
    const int bx = j & 31;
    const int bh = b * NHEADS + h;

    const int tid = threadIdx.x;
    const int kq = tid >> 6, lane = tid & 63;     // kq 0..7
    const int l31 = lane & 31, hi = lane >> 5;
    const int n = bx * 32 + l31;                  // q-row within bh
    const int kt0 = kq * 4;                       // this wave's first 32-k tile

    __shared__ float rs[8][32];

    short8 qf[4];
    const u16* qp = &q[((size_t)bh * NN + n) * UU + hi * 8];
    #pragma unroll
    for (int f = 0; f < 4; ++f) qf[f] = *(const short8*)(qp + f * 16);

    const u16* kbase = kmat + (size_t)bh * NN * UU + (size_t)(kt0 * 32 + l31) * UU + hi * 8;
    const unsigned int* mbase = adjpT + (((size_t)b) << 15) + n;

    unsigned int mv[4];
    #pragma unroll
    for (int i = 0; i < 4; ++i)
        mv[i] = mbase[(size_t)(kt0 + i) << 10] >> (4 * hi);

    const float L2E = 1.442695041f;
    const float C0 = -46.16624f;      // 1.4427 * (-32)
    const float CM = -100000.0f;      // masked-off -> exp2 == 0

    unsigned int eb[4][4][2];         // 32 VGPRs, fully statically indexed
    float rs0 = 0.f, rs1 = 0.f, rs2 = 0.f, rs3 = 0.f;

    short8 kf[4];
    #pragma unroll
    for (int f = 0; f < 4; ++f) kf[f] = *(const short8*)(kbase + f * 16);

    #pragma unroll
    for (int i = 0; i < 4; ++i) {
        f32x16 acc;
        #pragma unroll
        for (int jj = 0; jj < 16; ++jj) acc[jj] = 0.f;
        #pragma unroll
        for (int f = 0; f < 4; ++f)
            acc = __builtin_amdgcn_mfma_f32_32x32x16_bf16(kf[f], qf[f], acc, 0, 0, 0);
        if (i < 3) {
            const u16* kn = kbase + (size_t)(i + 1) * (32 * UU);
            #pragma unroll
            for (int f = 0; f < 4; ++f) kf[f] = *(const short8*)(kn + f * 16);
        }
        const unsigned int m2 = mv[i];
        #pragma unroll
        for (int g = 0; g < 4; ++g) {
            float e[4];
            #pragma unroll
            for (int r = 0; r < 4; ++r) {
                const int koff = r + 8 * g;
                float addv = ((m2 >> koff) & 1u) ? C0 : CM;
                e[r] = __builtin_amdgcn_exp2f(fmaf(L2E, acc[g * 4 + r], addv));
            }
            if (g == 0) rs0 += (e[0] + e[1]) + (e[2] + e[3]);
            else if (g == 1) rs1 += (e[0] + e[1]) + (e[2] + e[3]);
            else if (g == 2) rs2 += (e[0] + e[1]) + (e[2] + e[3]);
            else rs3 += (e[0] + e[1]) + (e[2] + e[3]);
            eb[i][g][0] = pkbf(e[0], e[1]);
            eb[i][g][1] = pkbf(e[2], e[3]);
        }
    }
    float rsum = (rs0 + rs1) + (rs2 + rs3);
    rsum += __shfl_xor(rsum, 32);          // lanes l / l+32 cover complementary k
    if (lane < 32) rs[kq][lane] = rsum;
    __syncthreads();
    const float total = ((rs[0][l31] + rs[1][l31]) + (rs[2][l31] + rs[3][l31]))
                      + ((rs[4][l31] + rs[5][l31]) + (rs[6][l31] + rs[7][l31]));
    const float scl = 16.0f / total;       // x16 folded; undone by 0.9/16 in hop

    u8* pb = P8 + (((size_t)bh) << 20) + (size_t)(n >> 4) * 16384
           + (n & 15) * 32 + hi * 16;
    #pragma unroll
    for (int i = 0; i < 4; ++i) {
        unsigned int dw[4];
        #pragma unroll
        for (int g = 0; g < 4; ++g) {      // reg quad g -> k bytes 8g+4hi .. +4
            float e0 = upk_lo(eb[i][g][0]) * scl;
            float e1 = upk_hi(eb[i][g][0]) * scl;
            float e2 = upk_lo(eb[i][g][1]) * scl;
            float e3 = upk_hi(eb[i][g][1]) * scl;
            int lo = __builtin_amdgcn_cvt_pk_fp8_f32(e0, e1, 0, false);
            dw[g] = (unsigned int)__builtin_amdgcn_cvt_pk_fp8_f32(e2, e3, lo, true);
        }
        unsigned int sendA = hi ? dw[0] : dw[2];
        unsigned int sendB = hi ? dw[1] : dw[3];
        unsigned int recvA = (unsigned int)__shfl_xor((int)sendA, 32);
        unsigned int recvB = (unsigned int)__shfl_xor((int)sendB, 32);
        uint4 o;
        o.x = hi ? recvA : dw[0];
        o.y = hi ? dw[2] : recvA;
        o.z = hi ? recvB : dw[1];
        o.w = hi ? dw[3] : recvB;
        *(uint4*)(pb + (size_t)(kt0 + i) * 512) = o;
    }
}

// ---------------------------------------------------------------------------
// K3: hop: z' = (0.9/16) * P16 @ z + 0.1 * v.  (best-measured R8/R15 variant:
// z staged via gl_lds16 into padded 66.5KB LDS; P loads 4-deep rolling
// register prefetch issued BEFORE the staging barrier; static indices.)
// last=0: write z'^T fp8;  last=1: write z' bf16 in [b,n,512] layout.
// ---------------------------------------------------------------------------
__global__ __launch_bounds__(512) void hop(
    const u8* __restrict__ P8, const u8* __restrict__ z8in,
    const u16* __restrict__ v, u8* __restrict__ z8out,
    u16* __restrict__ zbf_out, int last)
{
    const int b = blockIdx.z, h = blockIdx.y, rt = blockIdx.x;
    const int bh = b * NHEADS + h;
    const int tid = threadIdx.x;
    const int wave = tid >> 6, lane = tid & 63;
    const int ln = lane & 15, quad = lane >> 4;
    const int wrow = rt * 128 + wave * 16;

    __shared__ __align__(16) u8 zt[64 * 1040];

    const u8* zg = z8in + ((size_t)bh << 16);
    #pragma unroll
    for (int i = 0; i < 8; ++i) {
        int c = wave * 8 + i;
        gl_lds16(zg + (size_t)c * 1024 + lane * 16, (char*)zt + c * 1040);
    }

    const u8* pt = P8 + ((size_t)bh << 20) + (size_t)(rt * 8 + wave) * 16384
                 + ln * 32 + quad * 8;
    long pa[4];
    #pragma unroll
    for (int i = 0; i < 4; ++i) pa[i] = *(const long*)(pt + i * 512);

    __syncthreads();

    f32x4 acc[4];
    #pragma unroll
    for (int ci = 0; ci < 4; ++ci) acc[ci] = (f32x4){0.f, 0.f, 0.f, 0.f};

    #pragma unroll
    for (int kc = 0; kc < 32; ++kc) {
        long a = pa[kc & 3];
        if (kc + 4 < 32) pa[kc & 3] = *(const long*)(pt + (kc + 4) * 512);
        int kk = kc * 32;
        #pragma unroll
        for (int ci = 0; ci < 4; ++ci) {
            long bz = *(const long*)&zt[(ci * 16 + ln) * 1040 + kk + quad * 8];
            acc[ci] = __builtin_amdgcn_mfma_f32_16x16x32_fp8_fp8(a, bz, acc[ci], 0, 0, 0);
        }
    }

    if (last) {
        #pragma unroll
        for (int ci = 0; ci < 4; ++ci) {
            int col = ci * 16 + ln;
            #pragma unroll
            for (int r = 0; r < 4; ++r) {
                int row = wrow + quad * 4 + r;
                float vv = b2f(v[((size_t)bh * NN + row) * UU + col]);
                zbf_out[((size_t)(b * NN + row)) * HH + h * UU + col]
                    = f2b(0.05625f * acc[ci][r] + 0.1f * vv);
            }
        }
    } else {
        u8* zo = z8out + ((size_t)bh << 16);
        #pragma unroll
        for (int ci = 0; ci < 4; ++ci) {
            int col = ci * 16 + ln;
            float zv[4];
            #pragma unroll
            for (int r = 0; r < 4; ++r) {
                int row = wrow + quad * 4 + r;
                float vv = b2f(v[((size_t)bh * NN + row) * UU + col]);
                zv[r] = 0.05625f * acc[ci][r] + 0.1f * vv;
            }
            int lo = __builtin_amdgcn_cvt_pk_fp8_f32(zv[0], zv[1], 0, false);
            unsigned int dw = (unsigned int)__builtin_amdgcn_cvt_pk_fp8_f32(zv[2], zv[3], lo, true);
            *(unsigned int*)&zo[(size_t)col * 1024 + wrow + quad * 4] = dw;
        }
    }
}

// ---------------------------------------------------------------------------
// K4: y = x + z ; LayerNorm(y)*gamma + beta. x fp32, z bf16 [b,n,512], out fp32.
// ---------------------------------------------------------------------------
__global__ __launch_bounds__(256) void resid_ln(
    const float* __restrict__ x, const u16* __restrict__ z,
    const float* __restrict__ gamma, const float* __restrict__ beta,
    float* __restrict__ out)
{
    const int r = blockIdx.x * 4 + (threadIdx.x >> 6);
    const int lane = threadIdx.x & 63;
    const size_t base = (size_t)r * HH + lane * 8;

    const float4* xp = (const float4*)&x[base];
    float4 x0 = xp[0], x1 = xp[1];
    short8 zv = *(const short8*)&z[base];
    float y[8];
    y[0] = x0.x + b2f((u16)zv[0]); y[1] = x0.y + b2f((u16)zv[1]);
    y[2] = x0.z + b2f((u16)zv[2]); y[3] = x0.w + b2f((u16)zv[3]);
    y[4] = x1.x + b2f((u16)zv[4]); y[5] = x1.y + b2f((u16)zv[5]);
    y[6] = x1.z + b2f((u16)zv[6]); y[7] = x1.w + b2f((u16)zv[7]);

    float s = 0.f, sq = 0.f;
    #pragma unroll
    for (int j = 0; j < 8; ++j) { s += y[j]; sq += y[j] * y[j]; }
    #pragma unroll
    for (int off = 32; off >= 1; off >>= 1) {
        s  += __shfl_xor(s, off);
        sq += __shfl_xor(sq, off);
    }
    const float mu = s * (1.0f / HH);
    const float var = sq * (1.0f / HH) - mu * mu;
    const float rstd = rsqrtf(var + 1e-5f);

    const float4* gp = (const float4*)&gamma[lane * 8];
    const float4* bp = (const float4*)&beta[lane * 8];
    float4 g0 = gp[0], g1 = gp[1], b0 = bp[0], b1 = bp[1];

    float4 o0, o1;
    o0.x = (y[0] - mu) * rstd * g0.x + b0.x;
    o0.y = (y[1] - mu) * rstd * g0.y + b0.y;
    o0.z = (y[2] - mu) * rstd * g0.z + b0.z;
    o0.w = (y[3] - mu) * rstd * g0.w + b0.w;
    o1.x = (y[4] - mu) * rstd * g1.x + b1.x;
    o1.y = (y[5] - mu) * rstd * g1.y + b1.y;
    o1.z = (y[6] - mu) * rstd * g1.z + b1.z;
    o1.w = (y[7] - mu) * rstd * g1.w + b1.w;
    float4* op = (float4*)&out[base];
    op[0] = o0; op[1] = o1;
}

// ---------------------------------------------------------------------------
extern "C" void kernel_launch(void* const* d_in, const int* in_sizes, int n_in,
                              void* d_out, int out_size, void* d_ws, size_t ws_size,
                              hipStream_t stream)
{
    const float* x   = (const float*)d_in[0];
    const int* adj   = (const int*)d_in[1];
    const float* Wq  = (const float*)d_in[2];
    const float* bq  = (const float*)d_in[3];
    const float* Wk  = (const float*)d_in[4];
    const float* bk  = (const float*)d_in[5];
    const float* Wv  = (const float*)d_in[6];
    const float* bv  = (const float*)d_in[7];
    const float* gamma = (const float*)d_in[8];
    const float* beta  = (const float*)d_in[9];
    float* out = (float*)d_out;

    const size_t E = (size_t)BB * NN * HH;   // 4,194,304
    u16* ws16 = (u16*)d_ws;
    u16* xb = ws16;          // x as bf16, [b,n,512]
    u16* q  = ws16 + E;      // per-head layout [bh][n][64]
    u16* k  = ws16 + 2 * E;  // per-head layout
    u16* v  = ws16 + 3 * E;  // per-head layout
    u16* za = ws16 + 4 * E;  // final z, bf16, [b,n,512]
    u16* Wb = ws16 + 5 * E;  // 786,432 elems
    u8* base8 = (u8*)(ws16 + 5 * E + 786432);
    u8* P8  = base8;                          // 64 MB, tiled layout
    u8* z8a = base8 + ((size_t)64 << 20);     // 4 MB
    u8* z8b = z8a + ((size_t)4 << 20);        // 4 MB
    u8* v8t = z8b + ((size_t)4 << 20);        // 4 MB
    unsigned int* adjpT = (unsigned int*)(v8t + ((size_t)4 << 20));  // 1 MB

    prep<<<dim3(4480), 256, 0, stream>>>(x, Wq, Wk, Wv, adj, xb, Wb, adjpT);
    qkv_gemm<<<dim3(64, 4, 3), 256, 0, stream>>>(xb, Wb, bq, bk, bv, q, k, v, v8t);
    scores_softmax<<<dim3(2048), 512, 0, stream>>>(q, k, adjpT, P8);
    hop<<<dim3(8, NHEADS, BB), 512, 0, stream>>>(P8, v8t, v, z8a, za, 0);
    hop<<<dim3(8, NHEADS, BB), 512, 0, stream>>>(P8, z8a, v, z8b, za, 0);
    hop<<<dim3(8, NHEADS, BB), 512, 0, stream>>>(P8, z8b, v, z8a, za, 0);
    hop<<<dim3(8, NHEADS, BB), 512, 0, stream>>>(P8, z8a, v, z8b, za, 1);
    resid_ln<<<dim3(2048), 256, 0, stream>>>(x, za, gamma, beta, out);
}